// Round 2
// baseline (7931.956 us; speedup 1.0000x reference)
//
#include <hip/hip_runtime.h>
#include <math.h>

namespace {
constexpr int L_ = 4, H_ = 4, D_ = 128, DFF_ = 512, T_ = 64, B_ = 1024;
constexpr int S_ = 4, BOS_ = 4, DH_ = 32;
constexpr int NB = 4;                 // batch elements per block
constexpr int NBLK = B_ / NB;         // 256 blocks
constexpr int NTH = 512;              // threads per block

// workspace layout (float offsets) -- KV cache ONLY: exactly 256 MiB total.
constexpr size_t KC_BLK = (size_t)L_ * NB * T_ * D_;        // 131072 floats per block
constexpr size_t KC_OFF = 0;
constexpr size_t VC_OFF = KC_OFF + (size_t)NBLK * KC_BLK;   // 33,554,432 floats
}

__device__ __forceinline__ float4 ld4(const float* p) {
  return *reinterpret_cast<const float4*>(p);
}

__device__ __forceinline__ float wredsum64(float v) {
#pragma unroll
  for (int off = 32; off > 0; off >>= 1) v += __shfl_xor(v, off, 64);
  return v;
}

__device__ __forceinline__ float gelu_exact(float v) {
  return 0.5f * v * (1.0f + erff(v * 0.70710678118654752440f));
}

__global__ __launch_bounds__(NTH) void decode_kernel(
    const float* __restrict__ gumbel, const float* __restrict__ state_emb,
    const float* __restrict__ pos_emb,
    const float* __restrict__ ln1w, const float* __restrict__ ln1b,
    const float* __restrict__ wqkv, const float* __restrict__ bqkv,
    const float* __restrict__ wo, const float* __restrict__ bo,
    const float* __restrict__ ln2w, const float* __restrict__ ln2b,
    const float* __restrict__ w1, const float* __restrict__ b1,
    const float* __restrict__ w2, const float* __restrict__ b2,
    const float* __restrict__ fnw, const float* __restrict__ fnb,
    const float* __restrict__ headw, const float* __restrict__ headb,
    const int* __restrict__ nalpha, const int* __restrict__ nbeta,
    float* __restrict__ ws, float* __restrict__ out) {
  const int tid = threadIdx.x;
  const int blk = blockIdx.x;
  const int lane = tid & 63;
  const int wv = tid >> 6;
  const int slot = tid >> 2;   // 0..127 : weight-row slot
  const int dq = tid & 3;      // 0..3   : d-slice / element selector

  float* Kc = ws + KC_OFF + (size_t)blk * KC_BLK;
  float* Vc = ws + VC_OFF + (size_t)blk * KC_BLK;

  __shared__ __align__(16) float xres[NB][D_];
  __shared__ __align__(16) float xn[NB][D_];
  __shared__ __align__(16) float qbuf[NB][3 * D_];
  __shared__ __align__(16) float hbuf[NB][DFF_];
  __shared__ float sc[NB][H_][T_];
  __shared__ float wred[NTH / 64];
  __shared__ float logits[NB][S_];
  __shared__ int tok[NB], arem[NB], brem[NB];
  __shared__ float lpsum[NB];

  if (tid < NB) {
    tok[tid] = BOS_;
    arem[tid] = nalpha[0];
    brem[tid] = nbeta[0];
    lpsum[tid] = 0.f;
  }
  __syncthreads();

  for (int i = 0; i < T_; ++i) {
    // ---- embed: x = state_emb[tok] + pos_emb[i]
    {
      const int e = tid >> 7, d = tid & 127;
      xres[e][d] = state_emb[tok[e] * D_ + d] + pos_emb[i * D_ + d];
    }
    __syncthreads();

    for (int l = 0; l < L_; ++l) {
      // ---- LN1
      {
        const int e = tid >> 7, d = tid & 127;
        float v = xres[e][d];
        float s = wredsum64(v);
        if (lane == 0) wred[wv] = s;
        __syncthreads();
        float mu = (wred[2 * e] + wred[2 * e + 1]) * (1.f / 128.f);
        __syncthreads();
        float dv = v - mu;
        float s2 = wredsum64(dv * dv);
        if (lane == 0) wred[wv] = s2;
        __syncthreads();
        float var = (wred[2 * e] + wred[2 * e + 1]) * (1.f / 128.f);
        xn[e][d] = dv * (1.f / sqrtf(var + 1e-5f)) * ln1w[l * D_ + d] + ln1b[l * D_ + d];
      }
      __syncthreads();

      // ---- QKV: qbuf[e][o] = bqkv[o] + xn[e] . wqkv[l][o][:]
      // 4-lane group owns row o; lane dq reads d-slices {16j+4dq}; accumulates
      // for all NB elements; butterfly-reduce; lane dq writes element e=dq.
      {
#pragma unroll
        for (int p = 0; p < 3; ++p) {
          const int o = p * 128 + slot;
          const float* wrow = wqkv + ((size_t)l * 384 + o) * D_;
          float a0 = 0.f, a1 = 0.f, a2 = 0.f, a3 = 0.f;
#pragma unroll
          for (int j = 0; j < 8; ++j) {
            const int d0 = 16 * j + 4 * dq;
            const float4 w4 = ld4(wrow + d0);
            const float4 x0 = ld4(&xn[0][d0]);
            const float4 x1 = ld4(&xn[1][d0]);
            const float4 x2 = ld4(&xn[2][d0]);
            const float4 x3 = ld4(&xn[3][d0]);
            a0 += w4.x * x0.x + w4.y * x0.y + w4.z * x0.z + w4.w * x0.w;
            a1 += w4.x * x1.x + w4.y * x1.y + w4.z * x1.z + w4.w * x1.w;
            a2 += w4.x * x2.x + w4.y * x2.y + w4.z * x2.z + w4.w * x2.w;
            a3 += w4.x * x3.x + w4.y * x3.y + w4.z * x3.z + w4.w * x3.w;
          }
          a0 += __shfl_xor(a0, 1); a0 += __shfl_xor(a0, 2);
          a1 += __shfl_xor(a1, 1); a1 += __shfl_xor(a1, 2);
          a2 += __shfl_xor(a2, 1); a2 += __shfl_xor(a2, 2);
          a3 += __shfl_xor(a3, 1); a3 += __shfl_xor(a3, 2);
          float r = (dq == 0) ? a0 : (dq == 1) ? a1 : (dq == 2) ? a2 : a3;
          qbuf[dq][o] = r + bqkv[l * 384 + o];
        }
      }
      __syncthreads();

      // ---- write K,V into cache at position i
      {
        const int e = tid >> 7, d = tid & 127;
        size_t base = (((size_t)l * NB + e) * T_ + i) * D_ + d;
        Kc[base] = qbuf[e][D_ + d];
        Vc[base] = qbuf[e][2 * D_ + d];
      }
      __syncthreads();

      // ---- scores: sc[e][h][t] = (q . k_t)/sqrt(32), t<=i
      {
        const int pid = tid >> 5, j = tid & 31;
        const int e = pid >> 2, h = pid & 3;
        const float4* q4 = reinterpret_cast<const float4*>(&qbuf[e][h * DH_]);
        for (int t = j; t <= i; t += 32) {
          const float4* kp = reinterpret_cast<const float4*>(
              Kc + (((size_t)l * NB + e) * T_ + t) * D_ + h * DH_);
          float acc = 0.f;
#pragma unroll
          for (int k = 0; k < 8; ++k) {
            float4 a = q4[k], bv = kp[k];
            acc += a.x * bv.x + a.y * bv.y + a.z * bv.z + a.w * bv.w;
          }
          sc[e][h][t] = acc * 0.17677669529663687f;
        }
      }
      __syncthreads();

      // ---- softmax over t<=i (per (e,h), 32 threads)
      {
        const int pid = tid >> 5, j = tid & 31;
        const int e = pid >> 2, h = pid & 3;
        float m = -INFINITY;
        for (int t = j; t <= i; t += 32) m = fmaxf(m, sc[e][h][t]);
#pragma unroll
        for (int off = 16; off > 0; off >>= 1) m = fmaxf(m, __shfl_xor(m, off, 32));
        float sum = 0.f;
        for (int t = j; t <= i; t += 32) {
          float p = expf(sc[e][h][t] - m);
          sc[e][h][t] = p;
          sum += p;
        }
#pragma unroll
        for (int off = 16; off > 0; off >>= 1) sum += __shfl_xor(sum, off, 32);
        float inv = 1.f / sum;
        for (int t = j; t <= i; t += 32) sc[e][h][t] *= inv;
      }
      __syncthreads();

      // ---- ctx[e][d] = sum_t p[t] * V[t][d]  (reuse qbuf[.][0..127] as ctx)
      {
        const int e = tid >> 7, d = tid & 127, h = d >> 5;
        const float* vp = Vc + (((size_t)l * NB + e) * T_) * D_ + d;
        const float* pw = &sc[e][h][0];
        float acc = 0.f;
        int t = 0;
        for (; t + 4 <= i + 1; t += 4) {
          acc += pw[t] * vp[(size_t)t * D_];
          acc += pw[t + 1] * vp[(size_t)(t + 1) * D_];
          acc += pw[t + 2] * vp[(size_t)(t + 2) * D_];
          acc += pw[t + 3] * vp[(size_t)(t + 3) * D_];
        }
        for (; t <= i; ++t) acc += pw[t] * vp[(size_t)t * D_];
        qbuf[e][d] = acc;   // ctx overwrites q (no longer needed)
      }
      __syncthreads();

      // ---- x += ctx @ wo.T + bo
      {
        const int o = slot;
        const float* wrow = wo + ((size_t)l * 128 + o) * D_;
        float a0 = 0.f, a1 = 0.f, a2 = 0.f, a3 = 0.f;
#pragma unroll
        for (int j = 0; j < 8; ++j) {
          const int d0 = 16 * j + 4 * dq;
          const float4 w4 = ld4(wrow + d0);
          const float4 x0 = ld4(&qbuf[0][d0]);
          const float4 x1 = ld4(&qbuf[1][d0]);
          const float4 x2 = ld4(&qbuf[2][d0]);
          const float4 x3 = ld4(&qbuf[3][d0]);
          a0 += w4.x * x0.x + w4.y * x0.y + w4.z * x0.z + w4.w * x0.w;
          a1 += w4.x * x1.x + w4.y * x1.y + w4.z * x1.z + w4.w * x1.w;
          a2 += w4.x * x2.x + w4.y * x2.y + w4.z * x2.z + w4.w * x2.w;
          a3 += w4.x * x3.x + w4.y * x3.y + w4.z * x3.z + w4.w * x3.w;
        }
        a0 += __shfl_xor(a0, 1); a0 += __shfl_xor(a0, 2);
        a1 += __shfl_xor(a1, 1); a1 += __shfl_xor(a1, 2);
        a2 += __shfl_xor(a2, 1); a2 += __shfl_xor(a2, 2);
        a3 += __shfl_xor(a3, 1); a3 += __shfl_xor(a3, 2);
        float r = (dq == 0) ? a0 : (dq == 1) ? a1 : (dq == 2) ? a2 : a3;
        xres[dq][o] += r + bo[l * D_ + o];
      }
      __syncthreads();

      // ---- LN2
      {
        const int e = tid >> 7, d = tid & 127;
        float v = xres[e][d];
        float s = wredsum64(v);
        if (lane == 0) wred[wv] = s;
        __syncthreads();
        float mu = (wred[2 * e] + wred[2 * e + 1]) * (1.f / 128.f);
        __syncthreads();
        float dv = v - mu;
        float s2 = wredsum64(dv * dv);
        if (lane == 0) wred[wv] = s2;
        __syncthreads();
        float var = (wred[2 * e] + wred[2 * e + 1]) * (1.f / 128.f);
        xn[e][d] = dv * (1.f / sqrtf(var + 1e-5f)) * ln2w[l * D_ + d] + ln2b[l * D_ + d];
      }
      __syncthreads();

      // ---- FFN1 + exact GELU -> hbuf
      {
#pragma unroll
        for (int p = 0; p < 4; ++p) {
          const int o = p * 128 + slot;
          const float* wrow = w1 + ((size_t)l * DFF_ + o) * D_;
          float a0 = 0.f, a1 = 0.f, a2 = 0.f, a3 = 0.f;
#pragma unroll
          for (int j = 0; j < 8; ++j) {
            const int d0 = 16 * j + 4 * dq;
            const float4 w4 = ld4(wrow + d0);
            const float4 x0 = ld4(&xn[0][d0]);
            const float4 x1 = ld4(&xn[1][d0]);
            const float4 x2 = ld4(&xn[2][d0]);
            const float4 x3 = ld4(&xn[3][d0]);
            a0 += w4.x * x0.x + w4.y * x0.y + w4.z * x0.z + w4.w * x0.w;
            a1 += w4.x * x1.x + w4.y * x1.y + w4.z * x1.z + w4.w * x1.w;
            a2 += w4.x * x2.x + w4.y * x2.y + w4.z * x2.z + w4.w * x2.w;
            a3 += w4.x * x3.x + w4.y * x3.y + w4.z * x3.z + w4.w * x3.w;
          }
          a0 += __shfl_xor(a0, 1); a0 += __shfl_xor(a0, 2);
          a1 += __shfl_xor(a1, 1); a1 += __shfl_xor(a1, 2);
          a2 += __shfl_xor(a2, 1); a2 += __shfl_xor(a2, 2);
          a3 += __shfl_xor(a3, 1); a3 += __shfl_xor(a3, 2);
          float r = (dq == 0) ? a0 : (dq == 1) ? a1 : (dq == 2) ? a2 : a3;
          hbuf[dq][o] = gelu_exact(r + b1[l * DFF_ + o]);
        }
      }
      __syncthreads();

      // ---- FFN2: x += hbuf @ w2.T + b2
      {
        const int o = slot;
        const float* wrow = w2 + ((size_t)l * 128 + o) * DFF_;
        float a0 = 0.f, a1 = 0.f, a2 = 0.f, a3 = 0.f;
#pragma unroll 8
        for (int j = 0; j < 32; ++j) {
          const int d0 = 16 * j + 4 * dq;
          const float4 w4 = ld4(wrow + d0);
          const float4 x0 = ld4(&hbuf[0][d0]);
          const float4 x1 = ld4(&hbuf[1][d0]);
          const float4 x2 = ld4(&hbuf[2][d0]);
          const float4 x3 = ld4(&hbuf[3][d0]);
          a0 += w4.x * x0.x + w4.y * x0.y + w4.z * x0.z + w4.w * x0.w;
          a1 += w4.x * x1.x + w4.y * x1.y + w4.z * x1.z + w4.w * x1.w;
          a2 += w4.x * x2.x + w4.y * x2.y + w4.z * x2.z + w4.w * x2.w;
          a3 += w4.x * x3.x + w4.y * x3.y + w4.z * x3.z + w4.w * x3.w;
        }
        a0 += __shfl_xor(a0, 1); a0 += __shfl_xor(a0, 2);
        a1 += __shfl_xor(a1, 1); a1 += __shfl_xor(a1, 2);
        a2 += __shfl_xor(a2, 1); a2 += __shfl_xor(a2, 2);
        a3 += __shfl_xor(a3, 1); a3 += __shfl_xor(a3, 2);
        float r = (dq == 0) ? a0 : (dq == 1) ? a1 : (dq == 2) ? a2 : a3;
        xres[dq][o] += r + b2[l * D_ + o];
      }
      __syncthreads();
    }  // layers

    // ---- final LN
    {
      const int e = tid >> 7, d = tid & 127;
      float v = xres[e][d];
      float s = wredsum64(v);
      if (lane == 0) wred[wv] = s;
      __syncthreads();
      float mu = (wred[2 * e] + wred[2 * e + 1]) * (1.f / 128.f);
      __syncthreads();
      float dv = v - mu;
      float s2 = wredsum64(dv * dv);
      if (lane == 0) wred[wv] = s2;
      __syncthreads();
      float var = (wred[2 * e] + wred[2 * e + 1]) * (1.f / 128.f);
      xn[e][d] = dv * (1.f / sqrtf(var + 1e-5f)) * fnw[d] + fnb[d];
    }
    __syncthreads();

    // ---- head: logits[e][s]
    if (tid < 128) {
      const int e = tid >> 5, rest = tid & 31, s = rest >> 3, j = rest & 7;
      const float4* xv = reinterpret_cast<const float4*>(xn[e]);
      const float4* hw = reinterpret_cast<const float4*>(headw + s * D_);
      float acc = 0.f;
#pragma unroll
      for (int k = 4 * j; k < 4 * j + 4; ++k) {
        float4 a = xv[k], w = hw[k];
        acc += a.x * w.x + a.y * w.y + a.z * w.z + a.w * w.w;
      }
      acc += __shfl_xor(acc, 1);
      acc += __shfl_xor(acc, 2);
      acc += __shfl_xor(acc, 4);
      if (j == 0) logits[e][s] = acc + headb[s];
    }
    __syncthreads();

    // ---- validity mask + log-softmax + gumbel-argmax sample
    if (tid < NB) {
      const int e = tid;
      const int b = blk * NB + e;
      int a = arem[e], bb = brem[e];
      int oa = T_ - 1 - i;
      bool m[4];
      m[0] = (a <= oa) && (bb <= oa);
      m[1] = (bb > 0) && (a <= oa) && (bb - 1 <= oa);
      m[2] = (a > 0) && (a - 1 <= oa) && (bb <= oa);
      m[3] = (a > 0) && (bb > 0) && (a - 1 <= oa) && (bb - 1 <= oa);
      float mx = -INFINITY;
#pragma unroll
      for (int s = 0; s < 4; ++s)
        if (m[s]) mx = fmaxf(mx, logits[e][s]);
      float sum = 0.f;
      float lg[4];
#pragma unroll
      for (int s = 0; s < 4; ++s) {
        if (m[s]) {
          float z = logits[e][s] - mx;
          sum += expf(z);
          lg[s] = z;
        } else {
          lg[s] = -INFINITY;
        }
      }
      float lse = logf(sum);
      float best = -INFINITY;
      int bs = 0;
#pragma unroll
      for (int s = 0; s < 4; ++s) {
        float lp = lg[s] - lse;
        float y = lp + gumbel[(size_t)b * T_ * S_ + (size_t)i * S_ + s];
        if (y > best) { best = y; bs = s; }
      }
      lpsum[e] += lg[bs] - lse;
      out[(size_t)b * T_ + i] = (float)bs;
      tok[e] = bs;
      arem[e] = a - (bs >> 1);
      brem[e] = bb - (bs & 1);
    }
    __syncthreads();
  }  // steps

  if (tid < NB) out[(size_t)B_ * T_ + (size_t)blk * NB + tid] = lpsum[tid];
}

extern "C" void kernel_launch(void* const* d_in, const int* in_sizes, int n_in,
                              void* d_out, int out_size, void* d_ws, size_t ws_size,
                              hipStream_t stream) {
  const float* gumbel    = (const float*)d_in[0];
  const float* state_emb = (const float*)d_in[1];
  const float* pos_emb   = (const float*)d_in[2];
  const float* ln1w      = (const float*)d_in[3];
  const float* ln1b      = (const float*)d_in[4];
  const float* wqkv      = (const float*)d_in[5];
  const float* bqkv      = (const float*)d_in[6];
  const float* wo        = (const float*)d_in[7];
  const float* bo        = (const float*)d_in[8];
  const float* ln2w      = (const float*)d_in[9];
  const float* ln2b      = (const float*)d_in[10];
  const float* w1        = (const float*)d_in[11];
  const float* b1        = (const float*)d_in[12];
  const float* w2        = (const float*)d_in[13];
  const float* b2        = (const float*)d_in[14];
  const float* fnw       = (const float*)d_in[15];
  const float* fnb       = (const float*)d_in[16];
  const float* headw     = (const float*)d_in[17];
  const float* headb     = (const float*)d_in[18];
  const int* nalpha      = (const int*)d_in[19];
  const int* nbeta       = (const int*)d_in[20];
  float* ws = (float*)d_ws;
  float* out = (float*)d_out;

  decode_kernel<<<dim3(NBLK), dim3(NTH), 0, stream>>>(
      gumbel, state_emb, pos_emb, ln1w, ln1b, wqkv, bqkv, wo, bo, ln2w, ln2b,
      w1, b1, w2, b2, fnw, fnb, headw, headb, nalpha, nbeta, ws, out);
}